// Round 16
// baseline (103.583 us; speedup 1.0000x reference)
//
#include <hip/hip_runtime.h>
#include <stdint.h>

#define H 8
#define DH 96
#define L 2048
#define NB 2
#define D 768

typedef unsigned short u16;
typedef unsigned int u32;
typedef __attribute__((ext_vector_type(8))) __bf16 bf16x8;
typedef __attribute__((ext_vector_type(4))) float f32x4;
typedef __attribute__((ext_vector_type(4))) u32 u32x4;
typedef __attribute__((ext_vector_type(2))) u32 u32x2;
typedef __attribute__((ext_vector_type(4))) u16 u16x4;

// softmax scale folded with log2(e): 96^-0.5 * 1.4426950408889634
#define QSCALE 0.14724444f

static __device__ __forceinline__ u16 f2bf(float f) {
  union { __bf16 h; u16 u; } v;
  v.h = (__bf16)f;
  return v.u;
}

static __device__ __forceinline__ bf16x8 cvt8r(f32x4 a, f32x4 b) {
  bf16x8 r;
  r[0] = (__bf16)a[0]; r[1] = (__bf16)a[1]; r[2] = (__bf16)a[2]; r[3] = (__bf16)a[3];
  r[4] = (__bf16)b[0]; r[5] = (__bf16)b[1]; r[6] = (__bf16)b[2]; r[7] = (__bf16)b[3];
  return r;
}

// ---------------------------------------------------------------------------
// Fused QKV projection + RoPE (z=0: Q, z=1: K, z=2: V->V^T)  — unchanged r15
// (768 blocks = 3/CU one round; BM=64 x BN=192; wave-tile 32x96)
// ---------------------------------------------------------------------------
__global__ __launch_bounds__(256, 3)
void proj_qkv(const float* __restrict__ Qin, const float* __restrict__ Kin,
              const float* __restrict__ Vin,
              const float* __restrict__ Wq, const float* __restrict__ Wk,
              const float* __restrict__ Wv,
              const float* __restrict__ cq, const float* __restrict__ ck,
              u16* __restrict__ qo, u16* __restrict__ ko, u16* __restrict__ vo)
{
  __shared__ u16 a_lds[2][64 * 40];
  __shared__ u16 b_lds[2][192 * 40];
  const int tid = threadIdx.x;
  const int lane = tid & 63;
  const int w = tid >> 6;
  const int wr = w >> 1, wc = w & 1;
  const int fr = lane & 15;
  const int hi = lane >> 4;

  const int f = blockIdx.x;
  const int xcd = f & 7;
  const int g = f >> 3;          // 0..95
  const int bx = g & 3;
  const int h2 = g >> 2;         // 0..23
  const int byp = h2 & 7;
  const int z = h2 >> 3;
  const int by = xcd + 8 * byp;  // 0..63
  const int row0 = by * 64;
  const int col0 = bx * 192;

  const float* A = (z == 0) ? Qin : ((z == 1) ? Kin : Vin);
  const float* W = (z == 0) ? Wq : ((z == 1) ? Wk : Wv);

  const int arow = tid >> 2;
  const int acol = (tid & 3) * 8;
  const float* pA = A + (size_t)(row0 + arow) * D + acol;
  const float* pB0 = W + (size_t)(col0 + arow) * D + acol;
  const float* pB1 = pB0 + (size_t)64 * D;
  const float* pB2 = pB0 + (size_t)128 * D;

  f32x4 acc[2][6] = {};
  f32x4 Ra[2], Rb[6];

  auto issue = [&](int k) {
    Ra[0] = *(const f32x4*)(pA + k);
    Ra[1] = *(const f32x4*)(pA + k + 4);
    Rb[0] = *(const f32x4*)(pB0 + k);
    Rb[1] = *(const f32x4*)(pB0 + k + 4);
    Rb[2] = *(const f32x4*)(pB1 + k);
    Rb[3] = *(const f32x4*)(pB1 + k + 4);
    Rb[4] = *(const f32x4*)(pB2 + k);
    Rb[5] = *(const f32x4*)(pB2 + k + 4);
  };
  auto stage = [&](int bi) {
    *(bf16x8*)(&a_lds[bi][arow * 40 + acol]) = cvt8r(Ra[0], Ra[1]);
    *(bf16x8*)(&b_lds[bi][arow * 40 + acol]) = cvt8r(Rb[0], Rb[1]);
    *(bf16x8*)(&b_lds[bi][(arow + 64) * 40 + acol]) = cvt8r(Rb[2], Rb[3]);
    *(bf16x8*)(&b_lds[bi][(arow + 128) * 40 + acol]) = cvt8r(Rb[4], Rb[5]);
  };
  auto compute = [&](int bi) {
    bf16x8 af[2], bf[6];
#pragma unroll
    for (int m = 0; m < 2; m++)
      af[m] = *(const bf16x8*)(&a_lds[bi][(wr * 32 + m * 16 + fr) * 40 + hi * 8]);
#pragma unroll
    for (int n = 0; n < 6; n++)
      bf[n] = *(const bf16x8*)(&b_lds[bi][(wc * 96 + n * 16 + fr) * 40 + hi * 8]);
#pragma unroll
    for (int m = 0; m < 2; m++)
#pragma unroll
      for (int n = 0; n < 6; n++)
        acc[m][n] = __builtin_amdgcn_mfma_f32_16x16x32_bf16(af[m], bf[n], acc[m][n], 0, 0, 0);
  };

  issue(0);
  stage(0);
  __syncthreads();

  int cur = 0;
#pragma unroll 1
  for (int t = 0; t < 24; t++) {
    if (t + 1 < 24) issue((t + 1) * 32);
    compute(cur);
    if (t + 1 < 24) stage(cur ^ 1);
    __syncthreads();
    cur ^= 1;
  }

  const int hh = (col0 + wc * 96) / DH;
  if (z == 2) {
#pragma unroll
    for (int m = 0; m < 2; m++) {
      int rbase = row0 + wr * 32 + m * 16 + hi * 4;
#pragma unroll
      for (int n = 0; n < 6; n++) {
        int dd = n * 16 + fr;
#pragma unroll
        for (int r = 0; r < 4; r++) {
          int row = rbase + r;
          int b = row >> 11, l = row & (L - 1);
          vo[((size_t)((b * H + hh) * DH + dd)) * L + l] = f2bf(acc[m][n][r]);
        }
      }
    }
  } else {
    const float* coords = (z == 0) ? cq : ck;
    u16* outp = (z == 0) ? qo : ko;
    const float postscale = (z == 0) ? QSCALE : 1.0f;
    const float invf = exp2f(-(float)fr * 0.83048202372184058f);
#pragma unroll
    for (int m = 0; m < 2; m++) {
      int rbase = row0 + wr * 32 + m * 16 + hi * 4;
#pragma unroll
      for (int np = 0; np < 3; np++) {
        int n1 = np * 2;
        int dd1 = n1 * 16 + fr;
#pragma unroll
        for (int r = 0; r < 4; r++) {
          int row = rbase + r;
          int b = row >> 11, l = row & (L - 1);
          float coord = coords[((size_t)(b * L + l)) * 3 + np];
          float ang = coord * invf;
          float sn = __sinf(ang), cs = __cosf(ang);
          float x1 = acc[m][n1][r], x2 = acc[m][n1 + 1][r];
          size_t base = ((size_t)((b * H + hh) * L + l)) * DH;
          outp[base + dd1] = f2bf((x1 * cs - x2 * sn) * postscale);
          outp[base + dd1 + 16] = f2bf((x1 * sn + x2 * cs) * postscale);
        }
      }
    }
  }
}

// ---------------------------------------------------------------------------
// Flash attention: r15 structure + K staged via global_load_lds (width 16,
// lane-linear unpadded KSTR=96 -> deletes 3 reg-loads + 3 ds_write_b128 per
// thread per tile, -12 VGPR) + max3-fusable fmax tree. V stays reg-staged
// (sigma-permuted scatter can't use the DMA). One barrier/tile, defer-max,
// lane-local l, XCD swizzle.
// ---------------------------------------------------------------------------
#define KSTR 96
#define VSTR 72
#define NT   (L / 64)
__global__ __launch_bounds__(256, 2)
void attn_fwd(const u16* __restrict__ q_ws, const u16* __restrict__ k_ws,
              const u16* __restrict__ vt_ws, u16* __restrict__ ao)
{
  __shared__ u16 k_lds[2][64 * KSTR];
  __shared__ u16 vt_lds[2][96 * VSTR];
  const int tid = threadIdx.x;
  const int lane = tid & 63;
  const int w = tid >> 6;

  // swizzle: q-tiles of one bh share f%8 -> same XCD (K/V L2-resident)
  const int f = blockIdx.x;
  const int xr = f & 7;
  const int g = f >> 3;          // 0..63
  const int qx = g & 31;
  const int bh = xr + 8 * (g >> 5);
  const int q0 = qx * 64;

  const int fr = lane & 15;
  const int hi = lane >> 4;
  const int fko = hi * 8;

  const u16* kbase = k_ws + (size_t)bh * L * DH;
  const u16* vtbase = vt_ws + (size_t)bh * DH * L;

  // V staging offsets (columns sigma-permuted in 4-chunks)
  int vg_off[3], vl0_off[3], vl1_off[3];
#pragma unroll
  for (int it = 0; it < 3; it++) {
    int ch = tid + it * 256;
    int vrow = ch >> 3, vq = (ch & 7) * 2;
    vg_off[it] = vrow * L + vq * 4;
    int s0 = ((vq >> 3) << 5) | ((vq & 3) << 3) | (((vq >> 2) & 1) << 2);
    int vq1 = vq + 1;
    int s1 = ((vq1 >> 3) << 5) | ((vq1 & 3) << 3) | (((vq1 >> 2) & 1) << 2);
    vl0_off[it] = vrow * VSTR + s0;
    vl1_off[it] = vrow * VSTR + s1;
  }

  // K DMA: lane-linear; wave w, chunk it covers LDS bytes (w*64+it*256)*16..
  auto kdma = [&](int t, int bi) {
#pragma unroll
    for (int it = 0; it < 3; it++) {
      const u16* gp = kbase + (size_t)t * 64 * DH + ((size_t)(tid + it * 256)) * 8;
      u16* lp = &k_lds[bi][(size_t)(w * 64 + it * 256) * 8];
      __builtin_amdgcn_global_load_lds(
          (const __attribute__((address_space(1))) u32*)gp,
          (__attribute__((address_space(3))) u32*)lp, 16, 0, 0);
    }
  };

  // Q fragments (B-operand: lane fr = q-row)
  bf16x8 qf[3];
  const u16* qbase = q_ws + ((size_t)bh * L + q0 + w * 16 + fr) * DH;
#pragma unroll
  for (int ks = 0; ks < 3; ks++)
    qf[ks] = *(const bf16x8*)(qbase + ks * 32 + fko);

  f32x4 o[6] = {};
  float m_r = -1e30f, l_r = 0.f;

  u32x4 vreg[3];
  // prologue: tile 0 (K via DMA, V via regs) -> buf 0
  kdma(0, 0);
#pragma unroll
  for (int it = 0; it < 3; it++)
    vreg[it] = *(const u32x4*)(vtbase + vg_off[it]);
#pragma unroll
  for (int it = 0; it < 3; it++) {
    u32x2 lo = { vreg[it][0], vreg[it][1] };
    u32x2 hi2 = { vreg[it][2], vreg[it][3] };
    *(u32x2*)(&vt_lds[0][vl0_off[it]]) = lo;
    *(u32x2*)(&vt_lds[0][vl1_off[it]]) = hi2;
  }
  __syncthreads();

  int cur = 0;
  for (int t = 0; t < NT; t++) {
    if (t + 1 < NT) {  // K DMA + V reg prefetch into buf[cur^1]
      kdma(t + 1, cur ^ 1);
      const u16* vb = vtbase + (t + 1) * 64;
#pragma unroll
      for (int it = 0; it < 3; it++)
        vreg[it] = *(const u32x4*)(vb + vg_off[it]);
    }

    // S^T = K Q^T : lane fr = q, s[kf][reg] at k = kf*16+hi*4+reg
    f32x4 s[4] = {};
#pragma unroll
    for (int ks = 0; ks < 3; ks++)
#pragma unroll
      for (int kf = 0; kf < 4; kf++) {
        bf16x8 kfrag = *(const bf16x8*)(&k_lds[cur][(kf * 16 + fr) * KSTR + ks * 32 + fko]);
        s[kf] = __builtin_amdgcn_mfma_f32_16x16x32_bf16(kfrag, qf[ks], s[kf], 0, 0, 0);
      }

    // T13 defer-max; max3-fusable tree
    float a0 = fmaxf(fmaxf(s[0][0], s[0][1]), s[0][2]);
    float a1 = fmaxf(fmaxf(s[0][3], s[1][0]), s[1][1]);
    float a2 = fmaxf(fmaxf(s[1][2], s[1][3]), s[2][0]);
    float a3 = fmaxf(fmaxf(s[2][1], s[2][2]), s[2][3]);
    float a4 = fmaxf(fmaxf(s[3][0], s[3][1]), s[3][2]);
    float pmax = fmaxf(fmaxf(fmaxf(a0, a1), a2), fmaxf(fmaxf(a3, a4), s[3][3]));
    if (!__all(pmax - m_r <= 8.0f)) {
      float mx = fmaxf(pmax, __shfl_xor(pmax, 16));
      mx = fmaxf(mx, __shfl_xor(mx, 32));
      float mn = fmaxf(m_r, mx);
      float alpha = exp2f(m_r - mn);
      m_r = mn;
      l_r *= alpha;
#pragma unroll
      for (int df = 0; df < 6; df++)
#pragma unroll
        for (int r = 0; r < 4; r++)
          o[df][r] *= alpha;
    }

    float p[4][4];
    float rs = 0.f;
#pragma unroll
    for (int kf = 0; kf < 4; kf++)
#pragma unroll
      for (int r = 0; r < 4; r++) {
        float pv = exp2f(s[kf][r] - m_r);
        p[kf][r] = pv;
        rs += pv;
      }
    l_r += rs;  // lane-local; reduced in epilogue

    bf16x8 pt[2];
#pragma unroll
    for (int ks = 0; ks < 2; ks++)
#pragma unroll
      for (int j = 0; j < 8; j++)
        pt[ks][j] = (__bf16)p[2 * ks + (j >> 2)][j & 3];

    // O^T += V P^T
#pragma unroll
    for (int ks = 0; ks < 2; ks++)
#pragma unroll
      for (int df = 0; df < 6; df++) {
        bf16x8 vfrag = *(const bf16x8*)(&vt_lds[cur][(df * 16 + fr) * VSTR + ks * 32 + fko]);
        o[df] = __builtin_amdgcn_mfma_f32_16x16x32_bf16(vfrag, pt[ks], o[df], 0, 0, 0);
      }

    if (t + 1 < NT) {  // V write into buf[cur^1] (ordered by prev barrier)
#pragma unroll
      for (int it = 0; it < 3; it++) {
        u32x2 lo = { vreg[it][0], vreg[it][1] };
        u32x2 hi2 = { vreg[it][2], vreg[it][3] };
        *(u32x2*)(&vt_lds[cur ^ 1][vl0_off[it]]) = lo;
        *(u32x2*)(&vt_lds[cur ^ 1][vl1_off[it]]) = hi2;
      }
      __syncthreads();  // drains K-DMA (vmcnt) + V writes for tile t+1
      cur ^= 1;
    }
  }

  // epilogue: reduce l across the 4 hi-lanes of each q-row, then store
  float l_tot = l_r + __shfl_xor(l_r, 16);
  l_tot += __shfl_xor(l_tot, 32);
  const int b = bh >> 3, hh = bh & 7;
  const int l = q0 + w * 16 + fr;
  const float inv = 1.f / l_tot;
  u16* aop = ao + ((size_t)(b * L + l)) * D + hh * DH + hi * 4;
#pragma unroll
  for (int df = 0; df < 6; df++) {
    u16x4 pk;
#pragma unroll
    for (int r = 0; r < 4; r++)
      pk[r] = f2bf(o[df][r] * inv);
    *(u16x4*)(aop + df * 16) = pk;
  }
}

// ---------------------------------------------------------------------------
// Output projection: out = AO @ Wo^T; 64x64 tiles, XCD swizzle, 2-deep
// prefetch + dbuf LDS; bounds (256,3): 768 blocks = exactly 3/CU, one round.
// ---------------------------------------------------------------------------
__global__ __launch_bounds__(256, 3)
void gemm_out(const u16* __restrict__ A, const float* __restrict__ W,
              float* __restrict__ out)
{
  __shared__ u16 a_lds[2][64 * 40];
  __shared__ u16 b_lds[2][64 * 40];
  const int tid = threadIdx.x;
  const int lane = tid & 63;
  const int w = tid >> 6;
  const int wr = w >> 1, wc = w & 1;

  const int f = blockIdx.x;
  const int xr = f & 7;
  const int g = f >> 3;          // 0..95
  const int bx = g % 12;
  const int wq = g / 12;         // 0..7
  const int by = xr + 8 * wq;    // 0..63
  const int row0 = by * 64;
  const int col0 = bx * 64;

  f32x4 acc[2][2] = {};
  const int srow = tid >> 2;
  const int scol = (tid & 3) * 8;
  const u16* pA = A + (size_t)(row0 + srow) * D + scol;
  const float* pW = W + (size_t)(col0 + srow) * D + scol;
  const int fr = lane & 15;
  const int fk = (lane >> 4) * 8;

  auto issueG = [&](int k, u32x4* ra, f32x4* rb) {
    ra[0] = *(const u32x4*)(pA + k);
    rb[0] = *(const f32x4*)(pW + k);
    rb[1] = *(const f32x4*)(pW + k + 4);
  };
  auto writeG = [&](int bi, const u32x4* ra, const f32x4* rb) {
    *(u32x4*)(&a_lds[bi][srow * 40 + scol]) = ra[0];
    *(bf16x8*)(&b_lds[bi][srow * 40 + scol]) = cvt8r(rb[0], rb[1]);
  };
  auto computeG = [&](int bi) {
    bf16x8 af[2], bfr[2];
#pragma unroll
    for (int m = 0; m < 2; m++)
      af[m] = *(const bf16x8*)(&a_lds[bi][(wr * 32 + m * 16 + fr) * 40 + fk]);
#pragma unroll
    for (int n = 0; n < 2; n++)
      bfr[n] = *(const bf16x8*)(&b_lds[bi][(wc * 32 + n * 16 + fr) * 40 + fk]);
#pragma unroll
    for (int m = 0; m < 2; m++)
#pragma unroll
      for (int n = 0; n < 2; n++)
        acc[m][n] = __builtin_amdgcn_mfma_f32_16x16x32_bf16(af[m], bfr[n], acc[m][n], 0, 0, 0);
  };

  u32x4 raA[1], raB[1];
  f32x4 rbA[2], rbB[2];
  issueG(0, raB, rbB);
  writeG(0, raB, rbB);
  issueG(32, raA, rbA);
  __syncthreads();

  for (int k0 = 0; k0 < D; k0 += 64) {
    if (k0 + 64 < D) issueG(k0 + 64, raB, rbB);
    computeG(0);
    writeG(1, raA, rbA);
    __syncthreads();
    if (k0 + 96 < D) issueG(k0 + 96, raA, rbA);
    computeG(1);
    if (k0 + 64 < D) writeG(0, raB, rbB);
    __syncthreads();
  }

#pragma unroll
  for (int m = 0; m < 2; m++) {
    int rbase = row0 + wr * 32 + m * 16 + (lane >> 4) * 4;
#pragma unroll
    for (int n = 0; n < 2; n++) {
      int c = col0 + wc * 32 + n * 16 + fr;
#pragma unroll
      for (int r = 0; r < 4; r++)
        out[(size_t)(rbase + r) * D + c] = acc[m][n][r];
    }
  }
}

extern "C" void kernel_launch(void* const* d_in, const int* in_sizes, int n_in,
                              void* d_out, int out_size, void* d_ws, size_t ws_size,
                              hipStream_t stream) {
  (void)in_sizes; (void)n_in; (void)out_size;
  const float* Qin = (const float*)d_in[0];
  const float* Kin = (const float*)d_in[1];
  const float* Vin = (const float*)d_in[2];
  const float* cq  = (const float*)d_in[3];
  const float* ck  = (const float*)d_in[4];
  const float* Wq  = (const float*)d_in[5];
  const float* Wk  = (const float*)d_in[6];
  const float* Wv  = (const float*)d_in[7];
  const float* Wo  = (const float*)d_in[8];
  float* out = (float*)d_out;

  const size_t per = (size_t)NB * H * L * DH;  // 3,145,728 elems
  if (ws_size < 4 * per * sizeof(u16)) return;

  u16* q_ws  = (u16*)d_ws;
  u16* k_ws  = q_ws + per;
  u16* vt_ws = k_ws + per;
  u16* ao_ws = vt_ws + per;

  proj_qkv<<<dim3(768), dim3(256), 0, stream>>>(
      Qin, Kin, Vin, Wq, Wk, Wv, cq, ck, q_ws, k_ws, vt_ws);
  attn_fwd<<<dim3(32 * NB * H), dim3(256), 0, stream>>>(q_ws, k_ws, vt_ws, ao_ws);
  gemm_out<<<dim3(12 * 64), dim3(256), 0, stream>>>(ao_ws, Wo, out);
}

// Round 17
// 99.092 us; speedup vs baseline: 1.0453x; 1.0453x over previous
//
#include <hip/hip_runtime.h>
#include <stdint.h>

#define H 8
#define DH 96
#define L 2048
#define NB 2
#define D 768

typedef unsigned short u16;
typedef unsigned int u32;
typedef __attribute__((ext_vector_type(4))) __bf16 bf16x4;
typedef __attribute__((ext_vector_type(8))) __bf16 bf16x8;
typedef __attribute__((ext_vector_type(4))) float f32x4;
typedef __attribute__((ext_vector_type(16))) float f32x16;
typedef __attribute__((ext_vector_type(4))) u32 u32x4;
typedef __attribute__((ext_vector_type(2))) u32 u32x2;
typedef __attribute__((ext_vector_type(4))) u16 u16x4;

// softmax scale folded with log2(e): 96^-0.5 * 1.4426950408889634
#define QSCALE 0.14724444f

static __device__ __forceinline__ u16 f2bf(float f) {
  union { __bf16 h; u16 u; } v;
  v.h = (__bf16)f;
  return v.u;
}

static __device__ __forceinline__ bf16x8 cvt8r(f32x4 a, f32x4 b) {
  bf16x8 r;
  r[0] = (__bf16)a[0]; r[1] = (__bf16)a[1]; r[2] = (__bf16)a[2]; r[3] = (__bf16)a[3];
  r[4] = (__bf16)b[0]; r[5] = (__bf16)b[1]; r[6] = (__bf16)b[2]; r[7] = (__bf16)b[3];
  return r;
}

// ---------------------------------------------------------------------------
// Fused QKV projection + RoPE (z=0: Q, z=1: K, z=2: V->V^T)  — unchanged r15
// (768 blocks = 3/CU one round; BM=64 x BN=192; wave-tile 32x96)
// ---------------------------------------------------------------------------
__global__ __launch_bounds__(256, 3)
void proj_qkv(const float* __restrict__ Qin, const float* __restrict__ Kin,
              const float* __restrict__ Vin,
              const float* __restrict__ Wq, const float* __restrict__ Wk,
              const float* __restrict__ Wv,
              const float* __restrict__ cq, const float* __restrict__ ck,
              u16* __restrict__ qo, u16* __restrict__ ko, u16* __restrict__ vo)
{
  __shared__ u16 a_lds[2][64 * 40];
  __shared__ u16 b_lds[2][192 * 40];
  const int tid = threadIdx.x;
  const int lane = tid & 63;
  const int w = tid >> 6;
  const int wr = w >> 1, wc = w & 1;
  const int fr = lane & 15;
  const int hi = lane >> 4;

  const int f = blockIdx.x;
  const int xcd = f & 7;
  const int g = f >> 3;          // 0..95
  const int bx = g & 3;
  const int h2 = g >> 2;         // 0..23
  const int byp = h2 & 7;
  const int z = h2 >> 3;
  const int by = xcd + 8 * byp;  // 0..63
  const int row0 = by * 64;
  const int col0 = bx * 192;

  const float* A = (z == 0) ? Qin : ((z == 1) ? Kin : Vin);
  const float* W = (z == 0) ? Wq : ((z == 1) ? Wk : Wv);

  const int arow = tid >> 2;
  const int acol = (tid & 3) * 8;
  const float* pA = A + (size_t)(row0 + arow) * D + acol;
  const float* pB0 = W + (size_t)(col0 + arow) * D + acol;
  const float* pB1 = pB0 + (size_t)64 * D;
  const float* pB2 = pB0 + (size_t)128 * D;

  f32x4 acc[2][6] = {};
  f32x4 Ra[2], Rb[6];

  auto issue = [&](int k) {
    Ra[0] = *(const f32x4*)(pA + k);
    Ra[1] = *(const f32x4*)(pA + k + 4);
    Rb[0] = *(const f32x4*)(pB0 + k);
    Rb[1] = *(const f32x4*)(pB0 + k + 4);
    Rb[2] = *(const f32x4*)(pB1 + k);
    Rb[3] = *(const f32x4*)(pB1 + k + 4);
    Rb[4] = *(const f32x4*)(pB2 + k);
    Rb[5] = *(const f32x4*)(pB2 + k + 4);
  };
  auto stage = [&](int bi) {
    *(bf16x8*)(&a_lds[bi][arow * 40 + acol]) = cvt8r(Ra[0], Ra[1]);
    *(bf16x8*)(&b_lds[bi][arow * 40 + acol]) = cvt8r(Rb[0], Rb[1]);
    *(bf16x8*)(&b_lds[bi][(arow + 64) * 40 + acol]) = cvt8r(Rb[2], Rb[3]);
    *(bf16x8*)(&b_lds[bi][(arow + 128) * 40 + acol]) = cvt8r(Rb[4], Rb[5]);
  };
  auto compute = [&](int bi) {
    bf16x8 af[2], bf[6];
#pragma unroll
    for (int m = 0; m < 2; m++)
      af[m] = *(const bf16x8*)(&a_lds[bi][(wr * 32 + m * 16 + fr) * 40 + hi * 8]);
#pragma unroll
    for (int n = 0; n < 6; n++)
      bf[n] = *(const bf16x8*)(&b_lds[bi][(wc * 96 + n * 16 + fr) * 40 + hi * 8]);
#pragma unroll
    for (int m = 0; m < 2; m++)
#pragma unroll
      for (int n = 0; n < 6; n++)
        acc[m][n] = __builtin_amdgcn_mfma_f32_16x16x32_bf16(af[m], bf[n], acc[m][n], 0, 0, 0);
  };

  issue(0);
  stage(0);
  __syncthreads();

  int cur = 0;
#pragma unroll 1
  for (int t = 0; t < 24; t++) {
    if (t + 1 < 24) issue((t + 1) * 32);
    compute(cur);
    if (t + 1 < 24) stage(cur ^ 1);
    __syncthreads();
    cur ^= 1;
  }

  const int hh = (col0 + wc * 96) / DH;
  if (z == 2) {
#pragma unroll
    for (int m = 0; m < 2; m++) {
      int rbase = row0 + wr * 32 + m * 16 + hi * 4;
#pragma unroll
      for (int n = 0; n < 6; n++) {
        int dd = n * 16 + fr;
#pragma unroll
        for (int r = 0; r < 4; r++) {
          int row = rbase + r;
          int b = row >> 11, l = row & (L - 1);
          vo[((size_t)((b * H + hh) * DH + dd)) * L + l] = f2bf(acc[m][n][r]);
        }
      }
    }
  } else {
    const float* coords = (z == 0) ? cq : ck;
    u16* outp = (z == 0) ? qo : ko;
    const float postscale = (z == 0) ? QSCALE : 1.0f;
    const float invf = exp2f(-(float)fr * 0.83048202372184058f);
#pragma unroll
    for (int m = 0; m < 2; m++) {
      int rbase = row0 + wr * 32 + m * 16 + hi * 4;
#pragma unroll
      for (int np = 0; np < 3; np++) {
        int n1 = np * 2;
        int dd1 = n1 * 16 + fr;
#pragma unroll
        for (int r = 0; r < 4; r++) {
          int row = rbase + r;
          int b = row >> 11, l = row & (L - 1);
          float coord = coords[((size_t)(b * L + l)) * 3 + np];
          float ang = coord * invf;
          float sn = __sinf(ang), cs = __cosf(ang);
          float x1 = acc[m][n1][r], x2 = acc[m][n1 + 1][r];
          size_t base = ((size_t)((b * H + hh) * L + l)) * DH;
          outp[base + dd1] = f2bf((x1 * cs - x2 * sn) * postscale);
          outp[base + dd1 + 16] = f2bf((x1 * sn + x2 * cs) * postscale);
        }
      }
    }
  }
}

// ---------------------------------------------------------------------------
// Flash attention, 32x32x16 MFMA + k-split wave pairing.
// Waves (0,1): q[0:32) with k-halves [0:32)/[32:64); waves (2,3): q[32:64).
// Per wave per tile: 6 QK + 6 PV mfma_32x32x16 fed by 12 b128 reads (vs 24
// with 16x16) — 2x FLOP per LDS read at identical grid/wave geometry.
// Fragment maps (generalizing the verified 16x16 ones): A row / B col =
// lane&31, k = (lane>>5)*8+j; C col=lane&31, row=(reg&3)+8*(reg>>2)+4*(l>>5).
// k-tilde <-> k permutation = swap middle two 4-chunks per 16-group, applied
// to K/V at staging and to Q/P by register order. Independent online softmax
// per wave (k-half); epilogue flash-merge via LDS. Defer-max, XCD swizzle.
// ---------------------------------------------------------------------------
#define KSTR 104
#define VSTR 76
#define NT   (L / 64)
__global__ __launch_bounds__(256, 2)
void attn_fwd(const u16* __restrict__ q_ws, const u16* __restrict__ k_ws,
              const u16* __restrict__ vt_ws, u16* __restrict__ ao)
{
  __shared__ __attribute__((aligned(16))) u16 k_lds[2][64 * KSTR];
  __shared__ __attribute__((aligned(16))) u16 vt_lds[2][96 * VSTR];
  const int tid = threadIdx.x;
  const int lane = tid & 63;
  const int w = tid >> 6;

  // swizzle: q-tiles of one bh share f%8 -> same XCD (K/V L2-resident)
  const int f = blockIdx.x;
  const int xr = f & 7;
  const int g = f >> 3;          // 0..63
  const int qx = g & 31;
  const int bh = xr + 8 * (g >> 5);
  const int q0 = qx * 64;

  const int qlo = lane & 31;     // q within the wave's 32-row group / A row
  const int hi32 = lane >> 5;    // k-tilde half selector
  const int wq = w >> 1;         // q-subtile (0: rows 0-31, 1: rows 32-63)
  const int kk0 = (w & 1) * 32;  // wave's k-half within the 64-k tile

  const u16* kbase = k_ws + (size_t)bh * L * DH;
  const u16* vtbase = vt_ws + (size_t)bh * DH * L;

  // chunk-swap permutation (involution): 0->0, 1->2, 2->1, 3->3
  const int perm[4] = {0, 2, 1, 3};

  // K staging: thread covers 3x 8 d-elems; chunks {2c,2c+1} -> swapped cols.
  int kg_off[3], kl0[3], kl1[3];
  // V staging: 3x 8 k-elems of V^T rows; chunks swapped within 16-groups.
  int vg_off[3], vl0[3], vl1[3];
#pragma unroll
  for (int it = 0; it < 3; it++) {
    int ch = tid + it * 256;              // 0..767
    int krow = ch / 12, dc = ch % 12;     // 8 d at 8*dc
    kg_off[it] = krow * DH + dc * 8;
    int c0 = dc * 2;                      // even chunk
    kl0[it] = krow * KSTR + (c0 >> 2) * 16 + perm[c0 & 3] * 4;
    kl1[it] = krow * KSTR + (c0 >> 2) * 16 + perm[(c0 + 1) & 3] * 4;
    int vrow = ch >> 3, vq = (ch & 7) * 2;
    vg_off[it] = vrow * L + vq * 4;
    vl0[it] = vrow * VSTR + (vq >> 2) * 16 + perm[vq & 3] * 4;
    vl1[it] = vrow * VSTR + (vq >> 2) * 16 + perm[(vq + 1) & 3] * 4;
  }

  // Q B-frags: 6 d-slices; lane q = qlo; k-tilde = hi32*8+j ->
  // actual d = s*16 + {0-3,8-11}(+4 if hi32) : two 8B loads concatenated.
  bf16x8 qf[6];
  {
    const u16* qb = q_ws + ((size_t)bh * L + q0 + wq * 32 + qlo) * DH;
#pragma unroll
    for (int s = 0; s < 6; s++) {
      bf16x4 a = *(const bf16x4*)(qb + s * 16 + hi32 * 4);
      bf16x4 b = *(const bf16x4*)(qb + s * 16 + hi32 * 4 + 8);
      bf16x8 q;
      q[0] = a[0]; q[1] = a[1]; q[2] = a[2]; q[3] = a[3];
      q[4] = b[0]; q[5] = b[1]; q[6] = b[2]; q[7] = b[3];
      qf[s] = q;
    }
  }

  f32x16 o[3] = {};
  float m_r = -1e30f, l_r = 0.f;

  u32x4 kreg[3], vreg[3];
  auto kissue = [&](int t) {
    const u16* kb = kbase + (size_t)t * 64 * DH;
    const u16* vb = vtbase + t * 64;
#pragma unroll
    for (int it = 0; it < 3; it++) {
      kreg[it] = *(const u32x4*)(kb + kg_off[it]);
      vreg[it] = *(const u32x4*)(vb + vg_off[it]);
    }
  };
  auto kwrite = [&](int bi) {
#pragma unroll
    for (int it = 0; it < 3; it++) {
      u32x2 klo = { kreg[it][0], kreg[it][1] };
      u32x2 khi = { kreg[it][2], kreg[it][3] };
      *(u32x2*)(&k_lds[bi][kl0[it]]) = klo;
      *(u32x2*)(&k_lds[bi][kl1[it]]) = khi;
      u32x2 vlo = { vreg[it][0], vreg[it][1] };
      u32x2 vhi = { vreg[it][2], vreg[it][3] };
      *(u32x2*)(&vt_lds[bi][vl0[it]]) = vlo;
      *(u32x2*)(&vt_lds[bi][vl1[it]]) = vhi;
    }
  };

  kissue(0);
  kwrite(0);
  __syncthreads();

  int cur = 0;
  for (int t = 0; t < NT; t++) {
    if (t + 1 < NT) kissue(t + 1);  // latency hides under compute

    // S^T[k][q] for wave's 32k x 32q: 6 d-slices of mfma_32x32x16
    f32x16 s2 = {};
#pragma unroll
    for (int s = 0; s < 6; s++) {
      bf16x8 kfrag = *(const bf16x8*)(
          &k_lds[cur][(kk0 + qlo) * KSTR + s * 16 + hi32 * 8]);
      s2 = __builtin_amdgcn_mfma_f32_32x32x16_bf16(kfrag, qf[s], s2, 0, 0, 0);
    }

    // defer-max (T13): lane-local max over 16 regs; rescale rarely
    float a0 = fmaxf(fmaxf(s2[0], s2[1]), s2[2]);
    float a1 = fmaxf(fmaxf(s2[3], s2[4]), s2[5]);
    float a2 = fmaxf(fmaxf(s2[6], s2[7]), s2[8]);
    float a3 = fmaxf(fmaxf(s2[9], s2[10]), s2[11]);
    float a4 = fmaxf(fmaxf(s2[12], s2[13]), s2[14]);
    float pmax = fmaxf(fmaxf(fmaxf(a0, a1), a2), fmaxf(fmaxf(a3, a4), s2[15]));
    if (!__all(pmax - m_r <= 8.0f)) {
      float mx = fmaxf(pmax, __shfl_xor(pmax, 32));
      float mn = fmaxf(m_r, mx);
      float alpha = exp2f(m_r - mn);
      m_r = mn;
      l_r *= alpha;
#pragma unroll
      for (int db = 0; db < 3; db++)
#pragma unroll
        for (int r = 0; r < 16; r++)
          o[db][r] *= alpha;
    }

    float p[16];
    float rs = 0.f;
#pragma unroll
    for (int r = 0; r < 16; r++) {
      p[r] = exp2f(s2[r] - m_r);
      rs += p[r];
    }
    l_r += rs;

    // PV B-frags: slice s = p[s*8 + j] (derived: reg order matches k-tilde)
    bf16x8 pt[2];
#pragma unroll
    for (int s = 0; s < 2; s++)
#pragma unroll
      for (int j = 0; j < 8; j++)
        pt[s][j] = (__bf16)p[s * 8 + j];

    // O^T[d][q] += V P^T : 2 k-slices x 3 d-blocks
#pragma unroll
    for (int s = 0; s < 2; s++)
#pragma unroll
      for (int db = 0; db < 3; db++) {
        bf16x8 vfrag = *(const bf16x8*)(
            &vt_lds[cur][(db * 32 + qlo) * VSTR + kk0 + s * 16 + hi32 * 8]);
        o[db] = __builtin_amdgcn_mfma_f32_32x32x16_bf16(vfrag, pt[s], o[db], 0, 0, 0);
      }

    if (t + 1 < NT) {  // write buf last read at t-1 (ordered by prev barrier)
      kwrite(cur ^ 1);
      __syncthreads();
      cur ^= 1;
    }
  }

  // wave-level l (lane + its hi32 partner covers the wave's full 32k)
  float l_w = l_r + __shfl_xor(l_r, 32);

  // k-split flash merge: waves 1,3 publish (O, m, l); waves 0,2 combine.
  {
    float* xb = (float*)&k_lds[wq][0];   // wave pair (0,1)->buf0, (2,3)->buf1
    const int base = lane * 52;          // 52 f32 stride (16B-aligned chunks)
    if (w & 1) {
#pragma unroll
      for (int db = 0; db < 3; db++)
#pragma unroll
        for (int rg = 0; rg < 4; rg++) {
          f32x4 v = { o[db][rg * 4], o[db][rg * 4 + 1],
                      o[db][rg * 4 + 2], o[db][rg * 4 + 3] };
          *(f32x4*)&xb[base + db * 16 + rg * 4] = v;
        }
      xb[base + 48] = m_r;
      xb[base + 49] = l_w;
    }
    __syncthreads();
    if (!(w & 1)) {
      float m1 = xb[base + 48], l1 = xb[base + 49];
      float ms = fmaxf(m_r, m1);
      float c0 = exp2f(m_r - ms), c1 = exp2f(m1 - ms);
      float inv = 1.f / (l_w * c0 + l1 * c1);
      const int b = bh >> 3, hh = bh & 7;
      const int lrow = q0 + wq * 32 + qlo;
      u16* aop = ao + ((size_t)(b * L + lrow)) * D + hh * DH;
#pragma unroll
      for (int db = 0; db < 3; db++)
#pragma unroll
        for (int rg = 0; rg < 4; rg++) {
          f32x4 op = *(const f32x4*)&xb[base + db * 16 + rg * 4];
          u16x4 pk;
#pragma unroll
          for (int r4 = 0; r4 < 4; r4++)
            pk[r4] = f2bf((o[db][rg * 4 + r4] * c0 + op[r4] * c1) * inv);
          *(u16x4*)(aop + db * 32 + rg * 8 + hi32 * 4) = pk;
        }
    }
  }
}

// ---------------------------------------------------------------------------
// Output projection: out = AO @ Wo^T; 64x64 tiles, XCD swizzle, 2-deep
// prefetch + dbuf LDS; bounds (256,3): 768 blocks = exactly 3/CU, one round.
// ---------------------------------------------------------------------------
__global__ __launch_bounds__(256, 3)
void gemm_out(const u16* __restrict__ A, const float* __restrict__ W,
              float* __restrict__ out)
{
  __shared__ u16 a_lds[2][64 * 40];
  __shared__ u16 b_lds[2][64 * 40];
  const int tid = threadIdx.x;
  const int lane = tid & 63;
  const int w = tid >> 6;
  const int wr = w >> 1, wc = w & 1;

  const int f = blockIdx.x;
  const int xr = f & 7;
  const int g = f >> 3;          // 0..95
  const int bx = g % 12;
  const int wq = g / 12;         // 0..7
  const int by = xr + 8 * wq;    // 0..63
  const int row0 = by * 64;
  const int col0 = bx * 64;

  f32x4 acc[2][2] = {};
  const int srow = tid >> 2;
  const int scol = (tid & 3) * 8;
  const u16* pA = A + (size_t)(row0 + srow) * D + scol;
  const float* pW = W + (size_t)(col0 + srow) * D + scol;
  const int fr = lane & 15;
  const int fk = (lane >> 4) * 8;

  auto issueG = [&](int k, u32x4* ra, f32x4* rb) {
    ra[0] = *(const u32x4*)(pA + k);
    rb[0] = *(const f32x4*)(pW + k);
    rb[1] = *(const f32x4*)(pW + k + 4);
  };
  auto writeG = [&](int bi, const u32x4* ra, const f32x4* rb) {
    *(u32x4*)(&a_lds[bi][srow * 40 + scol]) = ra[0];
    *(bf16x8*)(&b_lds[bi][srow * 40 + scol]) = cvt8r(rb[0], rb[1]);
  };
  auto computeG = [&](int bi) {
    bf16x8 af[2], bfr[2];
#pragma unroll
    for (int m = 0; m < 2; m++)
      af[m] = *(const bf16x8*)(&a_lds[bi][(wr * 32 + m * 16 + fr) * 40 + fk]);
#pragma unroll
    for (int n = 0; n < 2; n++)
      bfr[n] = *(const bf16x8*)(&b_lds[bi][(wc * 32 + n * 16 + fr) * 40 + fk]);
#pragma unroll
    for (int m = 0; m < 2; m++)
#pragma unroll
      for (int n = 0; n < 2; n++)
        acc[m][n] = __builtin_amdgcn_mfma_f32_16x16x32_bf16(af[m], bfr[n], acc[m][n], 0, 0, 0);
  };

  u32x4 raA[1], raB[1];
  f32x4 rbA[2], rbB[2];
  issueG(0, raB, rbB);
  writeG(0, raB, rbB);
  issueG(32, raA, rbA);
  __syncthreads();

  for (int k0 = 0; k0 < D; k0 += 64) {
    if (k0 + 64 < D) issueG(k0 + 64, raB, rbB);
    computeG(0);
    writeG(1, raA, rbA);
    __syncthreads();
    if (k0 + 96 < D) issueG(k0 + 96, raA, rbA);
    computeG(1);
    if (k0 + 64 < D) writeG(0, raB, rbB);
    __syncthreads();
  }

#pragma unroll
  for (int m = 0; m < 2; m++) {
    int rbase = row0 + wr * 32 + m * 16 + (lane >> 4) * 4;
#pragma unroll
    for (int n = 0; n < 2; n++) {
      int c = col0 + wc * 32 + n * 16 + fr;
#pragma unroll
      for (int r = 0; r < 4; r++)
        out[(size_t)(rbase + r) * D + c] = acc[m][n][r];
    }
  }
}

extern "C" void kernel_launch(void* const* d_in, const int* in_sizes, int n_in,
                              void* d_out, int out_size, void* d_ws, size_t ws_size,
                              hipStream_t stream) {
  (void)in_sizes; (void)n_in; (void)out_size;
  const float* Qin = (const float*)d_in[0];
  const float* Kin = (const float*)d_in[1];
  const float* Vin = (const float*)d_in[2];
  const float* cq  = (const float*)d_in[3];
  const float* ck  = (const float*)d_in[4];
  const float* Wq  = (const float*)d_in[5];
  const float* Wk  = (const float*)d_in[6];
  const float* Wv  = (const float*)d_in[7];
  const float* Wo  = (const float*)d_in[8];
  float* out = (float*)d_out;

  const size_t per = (size_t)NB * H * L * DH;  // 3,145,728 elems
  if (ws_size < 4 * per * sizeof(u16)) return;

  u16* q_ws  = (u16*)d_ws;
  u16* k_ws  = q_ws + per;
  u16* vt_ws = k_ws + per;
  u16* ao_ws = vt_ws + per;

  proj_qkv<<<dim3(768), dim3(256), 0, stream>>>(
      Qin, Kin, Vin, Wq, Wk, Wv, cq, ck, q_ws, k_ws, vt_ws);
  attn_fwd<<<dim3(32 * NB * H), dim3(256), 0, stream>>>(q_ws, k_ws, vt_ws, ao_ws);
  gemm_out<<<dim3(12 * 64), dim3(256), 0, stream>>>(ao_ws, Wo, out);
}